// Round 1
// 909.644 us; speedup vs baseline: 1.0659x; 1.0659x over previous
//
#include <hip/hip_runtime.h>

#define Nn 50000
#define Ee 500000
#define Dd 128

typedef __attribute__((ext_vector_type(8))) short bf16x8;
typedef __attribute__((ext_vector_type(4))) float f32x4;

__device__ inline unsigned short f2bf(float f) {
  unsigned u = __float_as_uint(f);
  unsigned r = u + 0x7FFFu + ((u >> 16) & 1u);
  return (unsigned short)(r >> 16);
}

// ---------------- prep: bf16 weight transposes, bias fuse, x->bf16 ----------
__global__ __launch_bounds__(256) void prep_kernel(
    const float* __restrict__ x, const float* __restrict__ W_types,
    const float* __restrict__ b_types, const float* __restrict__ W_self,
    const float* __restrict__ W_e1, const float* __restrict__ W_e2,
    const float* __restrict__ b_e2,
    unsigned short* __restrict__ xbf, unsigned short* __restrict__ WTt,
    unsigned short* __restrict__ W1T, unsigned short* __restrict__ W2T,
    unsigned short* __restrict__ WsT, float* __restrict__ biasc) {
  int i = blockIdx.x * 256 + threadIdx.x;
  if (i < 65536) {                       // W_types -> [t][n][k] bf16
    int t = i >> 14, rem = i & 16383, n = rem >> 7, k = rem & 127;
    WTt[i] = f2bf(W_types[t * 16384 + k * 128 + n]);
  } else if (i < 81920) {                // W_e1 -> [n][k]
    int j = i - 65536; int n = j >> 7, k = j & 127;
    W1T[j] = f2bf(W_e1[k * 128 + n]);
  } else if (i < 98304) {                // W_e2 -> [n][k]
    int j = i - 81920; int n = j >> 7, k = j & 127;
    W2T[j] = f2bf(W_e2[k * 128 + n]);
  } else if (i < 114688) {               // W_self -> [n][k]
    int j = i - 98304; int n = j >> 7, k = j & 127;
    WsT[j] = f2bf(W_self[k * 128 + n]);
  } else if (i < 115200) {               // biasc[t][n] = b_types + b_e2
    int j = i - 114688; int n = j & 127;
    biasc[j] = b_types[j] + b_e2[n];
  } else if (i < 115200 + Nn * Dd) {     // x -> bf16
    int j = i - 115200;
    xbf[j] = f2bf(x[j]);
  }
}

// ---------------- counting sort of edges by type ----------------------------
__global__ __launch_bounds__(256) void hist_kernel(const int* __restrict__ et,
                                                   int* __restrict__ hist) {
  __shared__ int h[4];
  if (threadIdx.x < 4) h[threadIdx.x] = 0;
  __syncthreads();
  for (int i = blockIdx.x * 256 + threadIdx.x; i < Ee; i += gridDim.x * 256)
    atomicAdd(&h[et[i]], 1);
  __syncthreads();
  if (threadIdx.x < 4) atomicAdd(&hist[threadIdx.x], h[threadIdx.x]);
}

__global__ void prefix_kernel(const int* __restrict__ hist, int* __restrict__ cursor) {
  if (threadIdx.x == 0) {
    int s = 0;
    for (int t = 0; t < 4; ++t) { cursor[t] = s; s += hist[t]; }
  }
}

__global__ __launch_bounds__(256) void scatter_kernel(const int* __restrict__ et,
                                                      int* __restrict__ cursor,
                                                      int* __restrict__ sorted_eid) {
  __shared__ int lc[4], bb[4];
  if (threadIdx.x < 4) lc[threadIdx.x] = 0;
  __syncthreads();
  int per = (Ee + gridDim.x - 1) / gridDim.x;
  int s = blockIdx.x * per;
  int e = min(Ee, s + per);
  for (int i = s + (int)threadIdx.x; i < e; i += 256) atomicAdd(&lc[et[i]], 1);
  __syncthreads();
  if (threadIdx.x < 4) bb[threadIdx.x] = atomicAdd(&cursor[threadIdx.x], lc[threadIdx.x]);
  __syncthreads();
  if (threadIdx.x < 4) lc[threadIdx.x] = bb[threadIdx.x];
  __syncthreads();
  for (int i = s + (int)threadIdx.x; i < e; i += 256) {
    int p = atomicAdd(&lc[et[i]], 1);
    sorted_eid[p] = i;
  }
}

// ---------------- fused edge kernel: edge MLP + typed GEMM + scatter --------
// tile = 64 sorted edges; 4 waves, each wave owns a 16-row strip x 128 cols.
// mfma_f32_16x16x32_bf16 layouts (guide-verified):
//   A: lane holds A[m=lane&15][k=quad*8+j]   (16B contiguous in row-major [M][K])
//   B: lane holds B[k=quad*8+j][n=lane&15]   (16B contiguous in BT [N][K])
//   C/D: col=lane&15, row=quad*4+reg
//
// Restructured vs prior version:
//  - GEMM2 (h accumulator) runs FIRST and dies into the Hs LDS buffer, then
//    GEMM1+GEMM3 share the msg accumulator -> only one 32-reg acc live at a
//    time (was 64 live -> ~130 total regs -> 3 waves/SIMD; now target 5).
//  - ef and x A-fragments are loaded straight from global into registers
//    (ef: 2xfloat4/lane per k-slice, the 4 quads of a row form one full 128B
//    line; x: 16B/lane from L2-resident xbf). No Ax/Ae LDS staging -> LDS
//    35840 -> 17920 B, one __syncthreads instead of two.
//  - per-wave type mask via __any instead of block atomicOr.
__global__ __launch_bounds__(256, 5) void edge_kernel(
    const int* __restrict__ edge_index, const int* __restrict__ edge_type,
    const float* __restrict__ ef, const unsigned short* __restrict__ xbf,
    const unsigned short* __restrict__ WTt, const unsigned short* __restrict__ W1T,
    const unsigned short* __restrict__ W2T, const float* __restrict__ biasc,
    const float* __restrict__ b_e1, const int* __restrict__ sorted_eid,
    float* __restrict__ accum) {
  __shared__ unsigned short Hs[64][136];   // stride 136: 2-way banks only
  __shared__ int mrow[64];
  __shared__ int mtype[64];

  const int tid = threadIdx.x;
  const int tile0 = blockIdx.x * 64;

  if (tid < 64) {
    int i = tile0 + tid;
    int r = -1, t = 0;
    if (i < Ee) {
      int ee = sorted_eid[i];
      r = edge_index[ee];        // destination row
      t = edge_type[ee];
    }
    mrow[tid] = r;
    mtype[tid] = t;
  }

  const int w = tid >> 6, l = tid & 63, quad = l >> 4, lm = l & 15;
  const int mr = w * 16 + lm;  // this lane's A-fragment row within the tile

  const int i = tile0 + mr;
  const int e = sorted_eid[i < Ee ? i : Ee - 1];   // clamp: garbage rows masked in epilogue
  const int myt = edge_type[e];
  const int colnode = edge_index[Ee + e];          // source node

  // x A-fragments for GEMM1 — issue before the barrier to hide L2 latency
  bf16x8 ax[4];
  {
    const unsigned short* xp = xbf + colnode * Dd + quad * 8;
#pragma unroll
    for (int ks = 0; ks < 4; ++ks) ax[ks] = *(const bf16x8*)(xp + ks * 32);
  }

  // ---- GEMM2: H = ef @ W1 (A direct from global f32, packed in-register) ----
  f32x4 h[8];
#pragma unroll
  for (int c = 0; c < 8; ++c) h[c] = (f32x4){0.f, 0.f, 0.f, 0.f};
  const float* efp = ef + (long long)e * Dd + quad * 8;
#pragma unroll
  for (int ks = 0; ks < 4; ++ks) {
    float4 v0 = *(const float4*)(efp + ks * 32);
    float4 v1 = *(const float4*)(efp + ks * 32 + 4);
    bf16x8 a;
    a[0] = f2bf(v0.x); a[1] = f2bf(v0.y); a[2] = f2bf(v0.z); a[3] = f2bf(v0.w);
    a[4] = f2bf(v1.x); a[5] = f2bf(v1.y); a[6] = f2bf(v1.z); a[7] = f2bf(v1.w);
#pragma unroll
    for (int c = 0; c < 8; ++c) {
      bf16x8 b = *(const bf16x8*)(W1T + (c * 16 + lm) * Dd + ks * 32 + quad * 8);
      h[c] = __builtin_amdgcn_mfma_f32_16x16x32_bf16(a, b, h[c], 0, 0, 0);
    }
  }
  // +b1, relu, write H into Hs strip in A-layout (each wave owns its strip)
#pragma unroll
  for (int c = 0; c < 8; ++c) {
    int n = c * 16 + lm;
    float be = b_e1[n];
#pragma unroll
    for (int r4 = 0; r4 < 4; ++r4) {
      float v = h[c][r4] + be;
      v = v > 0.f ? v : 0.f;
      Hs[w * 16 + quad * 4 + r4][n] = f2bf(v);
    }
  }
  __syncthreads();   // covers Hs (wave-local, conservative) + mrow/mtype (cross-wave)

  f32x4 msg[8];
#pragma unroll
  for (int c = 0; c < 8; ++c) msg[c] = (f32x4){0.f, 0.f, 0.f, 0.f};

  // ---- GEMM1: typed transform, per-wave mask (sorted -> ~1 pass) ----
  for (int t = 0; t < 4; ++t) {
    if (!__any(myt == t)) continue;
    const unsigned short* Wt = WTt + t * Dd * Dd;
#pragma unroll
    for (int ks = 0; ks < 4; ++ks) {
      bf16x8 a = ax[ks];
      if (myt != t) a = (bf16x8){0, 0, 0, 0, 0, 0, 0, 0};
#pragma unroll
      for (int c = 0; c < 8; ++c) {
        bf16x8 b = *(const bf16x8*)(Wt + (c * 16 + lm) * Dd + ks * 32 + quad * 8);
        msg[c] = __builtin_amdgcn_mfma_f32_16x16x32_bf16(a, b, msg[c], 0, 0, 0);
      }
    }
  }

  // ---- GEMM3: msg += relu(H) @ W2 ----
#pragma unroll
  for (int ks = 0; ks < 4; ++ks) {
    bf16x8 a = *(const bf16x8*)&Hs[mr][ks * 32 + quad * 8];
#pragma unroll
    for (int c = 0; c < 8; ++c) {
      bf16x8 b = *(const bf16x8*)(W2T + (c * 16 + lm) * Dd + ks * 32 + quad * 8);
      msg[c] = __builtin_amdgcn_mfma_f32_16x16x32_bf16(a, b, msg[c], 0, 0, 0);
    }
  }

  // epilogue: + per-type bias (+b_e2 fused) and atomic scatter to accum[row]
#pragma unroll
  for (int r4 = 0; r4 < 4; ++r4) {
    int m = w * 16 + quad * 4 + r4;
    int rn = mrow[m];
    if (rn < 0) continue;
    int t = mtype[m];
    float* dst = accum + (long long)rn * Dd;
    const float* bc = biasc + t * Dd;
#pragma unroll
    for (int c = 0; c < 8; ++c) {
      int n = c * 16 + lm;
      unsafeAtomicAdd(dst + n, msg[c][r4] + bc[n]);
    }
  }
}

// ---------------- self transform + LayerNorm + ReLU -------------------------
__global__ __launch_bounds__(256) void selfln_kernel(
    const unsigned short* __restrict__ xbf, const unsigned short* __restrict__ WsT,
    const float* __restrict__ b_self, const float* __restrict__ accum,
    const float* __restrict__ ln_g, const float* __restrict__ ln_b,
    float* __restrict__ out) {
  __shared__ unsigned short Axl[64][136];
  __shared__ float S[64][132];
  __shared__ float P1[64][4], P2[64][4];
  __shared__ float MU[64], RS[64];

  const int tid = threadIdx.x;
  const int tile0 = blockIdx.x * 64;
  {
    const int r = tid >> 2, c0 = (tid & 3) * 32;
    int row = tile0 + r;
    if (row < Nn) {
      const uint4* xs = (const uint4*)(xbf + row * Dd + c0);
      uint4* xd = (uint4*)&Axl[r][c0];
      xd[0] = xs[0]; xd[1] = xs[1]; xd[2] = xs[2]; xd[3] = xs[3];
    } else {
      uint4 z = {0, 0, 0, 0};
      uint4* xd = (uint4*)&Axl[r][c0];
      xd[0] = z; xd[1] = z; xd[2] = z; xd[3] = z;
    }
  }
  __syncthreads();

  const int w = tid >> 6, l = tid & 63, quad = l >> 4, lm = l & 15;
  const int mr = w * 16 + lm;
  f32x4 acc[8];
#pragma unroll
  for (int c = 0; c < 8; ++c) acc[c] = (f32x4){0.f, 0.f, 0.f, 0.f};
#pragma unroll
  for (int ks = 0; ks < 4; ++ks) {
    bf16x8 a = *(const bf16x8*)&Axl[mr][ks * 32 + quad * 8];
#pragma unroll
    for (int c = 0; c < 8; ++c) {
      bf16x8 b = *(const bf16x8*)(WsT + (c * 16 + lm) * Dd + ks * 32 + quad * 8);
      acc[c] = __builtin_amdgcn_mfma_f32_16x16x32_bf16(a, b, acc[c], 0, 0, 0);
    }
  }
#pragma unroll
  for (int c = 0; c < 8; ++c) {
    int n = c * 16 + lm;
    float bs = b_self[n];
#pragma unroll
    for (int r4 = 0; r4 < 4; ++r4) {
      int m = w * 16 + quad * 4 + r4;
      int grow = tile0 + m;
      float v = acc[c][r4] + bs;
      if (grow < Nn) v += accum[(long long)grow * Dd + n];
      S[m][n] = v;
    }
  }
  __syncthreads();
  {
    const int r = tid >> 2, sgi = tid & 3, c0 = sgi * 32;
    float s1 = 0.f, s2 = 0.f;
#pragma unroll
    for (int j = 0; j < 32; ++j) { float v = S[r][c0 + j]; s1 += v; s2 += v * v; }
    P1[r][sgi] = s1; P2[r][sgi] = s2;
  }
  __syncthreads();
  if (tid < 64) {
    float s1 = P1[tid][0] + P1[tid][1] + P1[tid][2] + P1[tid][3];
    float s2 = P2[tid][0] + P2[tid][1] + P2[tid][2] + P2[tid][3];
    float mu = s1 * (1.f / 128.f);
    float var = s2 * (1.f / 128.f) - mu * mu;
    MU[tid] = mu;
    RS[tid] = rsqrtf(var + 1e-5f);
  }
  __syncthreads();
  {
    const int r = tid >> 2, c0 = (tid & 3) * 32;
    int row = tile0 + r;
    if (row < Nn) {
      float mu = MU[r], rs = RS[r];
      float* op = out + (long long)row * Dd + c0;
#pragma unroll
      for (int j = 0; j < 32; ++j) {
        float v = (S[r][c0 + j] - mu) * rs * ln_g[c0 + j] + ln_b[c0 + j];
        op[j] = v > 0.f ? v : 0.f;
      }
    }
  }
}

// ---------------- launch ----------------------------------------------------
extern "C" void kernel_launch(void* const* d_in, const int* in_sizes, int n_in,
                              void* d_out, int out_size, void* d_ws, size_t ws_size,
                              hipStream_t stream) {
  (void)in_sizes; (void)n_in; (void)out_size; (void)ws_size;
  const float* x       = (const float*)d_in[0];
  const int*   eidx    = (const int*)d_in[1];
  const int*   etype   = (const int*)d_in[2];
  const float* ef      = (const float*)d_in[3];
  const float* W_types = (const float*)d_in[4];
  const float* b_types = (const float*)d_in[5];
  const float* W_self  = (const float*)d_in[6];
  const float* b_self  = (const float*)d_in[7];
  const float* W_e1    = (const float*)d_in[8];
  const float* b_e1    = (const float*)d_in[9];
  const float* W_e2    = (const float*)d_in[10];
  const float* b_e2    = (const float*)d_in[11];
  const float* ln_g    = (const float*)d_in[12];
  const float* ln_b    = (const float*)d_in[13];
  float* out = (float*)d_out;

  char* ws = (char*)d_ws;
  // layout (all offsets 512B-aligned)
  int*            ints   = (int*)ws;                              // [0..3] hist, [4..7] cursor
  float*          accum  = (float*)(ws + 512);                    // N*D f32 = 25,600,000 B
  unsigned short* xbf    = (unsigned short*)(ws + 512 + 25600000);            // 12,800,000 B
  unsigned short* WTt    = (unsigned short*)(ws + 512 + 25600000 + 12800000); // 131,072 B
  unsigned short* W1T    = WTt + 4 * 128 * 128;
  unsigned short* W2T    = W1T + 128 * 128;
  unsigned short* WsT    = W2T + 128 * 128;
  float*          biasc  = (float*)(WsT + 128 * 128);             // 2,048 B
  int*            sorted = (int*)((char*)biasc + 2048);           // E*4 = 2,000,000 B

  hipMemsetAsync(ws, 0, 512 + (size_t)Nn * Dd * 4, stream);  // hist+cursor+accum

  prep_kernel<<<25450, 256, 0, stream>>>(x, W_types, b_types, W_self, W_e1, W_e2,
                                         b_e2, xbf, WTt, W1T, W2T, WsT, biasc);
  hist_kernel<<<512, 256, 0, stream>>>(etype, ints);
  prefix_kernel<<<1, 64, 0, stream>>>(ints, ints + 4);
  scatter_kernel<<<512, 256, 0, stream>>>(etype, ints + 4, sorted);
  edge_kernel<<<(Ee + 63) / 64, 256, 0, stream>>>(eidx, etype, ef, xbf, WTt, W1T,
                                                  W2T, biasc, b_e1, sorted, accum);
  selfln_kernel<<<(Nn + 63) / 64, 256, 0, stream>>>(xbf, WsT, b_self, accum, ln_g,
                                                    ln_b, out);
}